// Round 1
// baseline (340.420 us; speedup 1.0000x reference)
//
#include <hip/hip_runtime.h>
#include <hip/hip_bf16.h>

// Fused Swin window attention for MI355X (gfx950).
// Layout: one block per 8x8 window (2048 blocks), 256 threads (4 waves).
// Pipeline per block:
//   1. stage x window (64x256 fp32 -> bf16) into LDS
//   2. QKV GEMM (64x256 @ 256x768) via mfma_f32_16x16x32_bf16, weights bf16 from L2
//   3. per head: S = q k^T (K=32, 1 k-step), +scale +bias, wave-parallel softmax,
//      PV, out-proj slice accumulated into persistent fp32 accumulators
//   4. single fp32 write of 64x256 output tile
// Prep kernel converts w_qkv/w_out to transposed bf16 and builds the 64x64 bias
// table in d_ws (needs 540,672 bytes of workspace).

typedef __attribute__((ext_vector_type(8))) short bf16x8;
typedef __attribute__((ext_vector_type(4))) float f32x4;

__device__ __forceinline__ f32x4 mfma16(bf16x8 a, bf16x8 b, f32x4 c) {
  return __builtin_amdgcn_mfma_f32_16x16x32_bf16(a, b, c, 0, 0, 0);
}

__device__ __forceinline__ unsigned short f2bf(float f) {
  union { float f; unsigned u; } v; v.f = f;
  unsigned r = v.u + 0x7fffu + ((v.u >> 16) & 1u);
  return (unsigned short)(r >> 16);
}

#define SCALE 0.17677669529663687f

// LDS strides (elements). Odd multiples of 8 elements (16B) -> bank-friendly.
#define XSTR 264   // x/q/k tiles: [64][256] + 8 pad
#define VSTR 72    // vT tile: [256][64] + 8 pad
#define PSTR 72    // p tile:  [64][64] + 8 pad
#define OSTR 40    // oh tile: [64][32] + 8 pad

// smem element offsets (unsigned short units)
#define OFF_X  0
#define OFF_Q  16896            // 64*264
#define OFF_K  33792
#define OFF_VT 50688
#define OFF_P  0                // reuses x region (x dead after QKV GEMM)
#define OFF_OH 4608             // 64*72, still inside x region
#define SMEM_ELTS 69120         // 50688 + 256*72 = 138240 bytes

__global__ void prep_kernel(const float* __restrict__ w_qkv,
                            const float* __restrict__ w_out,
                            const float* __restrict__ pos_emb,
                            unsigned short* __restrict__ wqkvT,
                            unsigned short* __restrict__ woutT,
                            float* __restrict__ bias64) {
  const int stride = gridDim.x * blockDim.x;
  const int tid = blockIdx.x * blockDim.x + threadIdx.x;
  // wqkvT[n][k] = bf16(w_qkv[k][n]); n in [0,768), k in [0,256)
  for (int i = tid; i < 768 * 256; i += stride) {
    int n = i >> 8, k = i & 255;
    wqkvT[i] = f2bf(w_qkv[k * 768 + n]);
  }
  // woutT[n][k] = bf16(w_out[k][n]); n,k in [0,256)
  for (int i = tid; i < 256 * 256; i += stride) {
    int n = i >> 8, k = i & 255;
    woutT[i] = f2bf(w_out[k * 256 + n]);
  }
  // bias64[i][j] = pos_emb[(jx-ix+7)][(jy-iy+7)], idx i -> (x=i>>3, y=i&7)
  for (int i = tid; i < 64 * 64; i += stride) {
    int a = i >> 6, b = i & 63;
    int d0 = (b >> 3) - (a >> 3) + 7;
    int d1 = (b & 7) - (a & 7) + 7;
    bias64[i] = pos_emb[d0 * 15 + d1];
  }
}

__global__ __launch_bounds__(256, 1)
void winattn_kernel(const float* __restrict__ x,
                    const unsigned short* __restrict__ wqkvT,
                    const unsigned short* __restrict__ woutT,
                    const float* __restrict__ bias64,
                    const float* __restrict__ b_out,
                    float* __restrict__ out) {
  __shared__ unsigned short smem[SMEM_ELTS];

  const int tid = threadIdx.x;
  const int lane = tid & 63;
  const int w = tid >> 6;        // wave id 0..3
  const int l15 = lane & 15;
  const int lq = lane >> 4;      // quarter 0..3

  const int bid = blockIdx.x;
  const int win = bid & 255;
  const int img = bid >> 8;      // b*4 + l
  const int wy = win >> 4, wx = win & 15;

  unsigned short* x_lds = smem + OFF_X;
  unsigned short* q_lds = smem + OFF_Q;
  unsigned short* k_lds = smem + OFF_K;
  unsigned short* vT_lds = smem + OFF_VT;
  unsigned short* p_lds = smem + OFF_P;
  unsigned short* oh_lds = smem + OFF_OH;

  const f32x4 zero4 = {0.f, 0.f, 0.f, 0.f};

  // ---------- phase 1: stage x window -> bf16 LDS ----------
  {
    const size_t img_base = (size_t)img * 128 * 128 * 256;
#pragma unroll
    for (int r = 0; r < 16; ++r) {
      int p = r * 4 + w;                 // pixel 0..63, per-wave coalesced rows
      int py = p >> 3, px = p & 7;
      const float* src = x + img_base +
          (((size_t)(wy * 8 + py) * 128) + (wx * 8 + px)) * 256 + lane * 4;
      float4 v4 = *(const float4*)src;
      unsigned short* dst = &x_lds[p * XSTR + lane * 4];
      dst[0] = f2bf(v4.x); dst[1] = f2bf(v4.y);
      dst[2] = f2bf(v4.z); dst[3] = f2bf(v4.w);
    }
  }
  __syncthreads();

  // ---------- phase 2: QKV GEMM (64x768 = x @ w_qkv) ----------
  // 4 column chunks of 192; wave w owns cols [c*192 + w*48, +48) (3 tiles) x 4 row tiles.
  for (int c = 0; c < 4; ++c) {
    f32x4 acc[4][3];
#pragma unroll
    for (int rt = 0; rt < 4; ++rt)
#pragma unroll
      for (int ct = 0; ct < 3; ++ct) acc[rt][ct] = zero4;

    const int ncb = c * 192 + w * 48;
#pragma unroll
    for (int kk = 0; kk < 8; ++kk) {
      const int ko = kk * 32 + lq * 8;
      bf16x8 a[4], b[3];
#pragma unroll
      for (int rt = 0; rt < 4; ++rt)
        a[rt] = *(const bf16x8*)&x_lds[(rt * 16 + l15) * XSTR + ko];
#pragma unroll
      for (int ct = 0; ct < 3; ++ct)
        b[ct] = *(const bf16x8*)&wqkvT[(size_t)(ncb + ct * 16 + l15) * 256 + ko];
#pragma unroll
      for (int rt = 0; rt < 4; ++rt)
#pragma unroll
        for (int ct = 0; ct < 3; ++ct)
          acc[rt][ct] = mfma16(a[rt], b[ct], acc[rt][ct]);
    }
    // epilogue: scatter to q / k / vT (bf16)
#pragma unroll
    for (int rt = 0; rt < 4; ++rt) {
#pragma unroll
      for (int ct = 0; ct < 3; ++ct) {
        const int ng = ncb + ct * 16 + l15;   // 16-aligned tile => branch uniform
#pragma unroll
        for (int r = 0; r < 4; ++r) {
          const int row = rt * 16 + lq * 4 + r;
          const unsigned short bv = f2bf(acc[rt][ct][r]);
          if (ng < 256)        q_lds[row * XSTR + ng] = bv;
          else if (ng < 512)   k_lds[row * XSTR + (ng - 256)] = bv;
          else                 vT_lds[(ng - 512) * VSTR + row] = bv;
        }
      }
    }
  }
  __syncthreads();   // x region now dead; p/oh reuse it below

  // ---------- phase 3: per-head attention + fused out-proj ----------
  // Wave w owns score/output rows [w*16, w*16+16).
  float bias_r[4][4];
#pragma unroll
  for (int ct = 0; ct < 4; ++ct)
#pragma unroll
    for (int r = 0; r < 4; ++r)
      bias_r[ct][r] = bias64[(w * 16 + lq * 4 + r) * 64 + ct * 16 + l15];

  f32x4 ACC[16];
#pragma unroll
  for (int ct = 0; ct < 16; ++ct) ACC[ct] = zero4;

  for (int h = 0; h < 8; ++h) {
    // S = q k^T : 1x4 tiles, K=32 (single k-step)
    f32x4 s[4];
    const bf16x8 aq = *(const bf16x8*)&q_lds[(w * 16 + l15) * XSTR + h * 32 + lq * 8];
#pragma unroll
    for (int ct = 0; ct < 4; ++ct) {
      const bf16x8 bk = *(const bf16x8*)&k_lds[(ct * 16 + l15) * XSTR + h * 32 + lq * 8];
      s[ct] = mfma16(aq, bk, zero4);
    }
    // scale + bias
#pragma unroll
    for (int ct = 0; ct < 4; ++ct)
#pragma unroll
      for (int r = 0; r < 4; ++r)
        s[ct][r] = s[ct][r] * SCALE + bias_r[ct][r];

    // row softmax (row lives in the 16 lanes of one quarter, 4 regs each)
    float rsum[4];
#pragma unroll
    for (int r = 0; r < 4; ++r) {
      float mx = fmaxf(fmaxf(s[0][r], s[1][r]), fmaxf(s[2][r], s[3][r]));
      mx = fmaxf(mx, __shfl_xor(mx, 1));
      mx = fmaxf(mx, __shfl_xor(mx, 2));
      mx = fmaxf(mx, __shfl_xor(mx, 4));
      mx = fmaxf(mx, __shfl_xor(mx, 8));
      float sm = 0.f;
#pragma unroll
      for (int ct = 0; ct < 4; ++ct) {
        float e = __expf(s[ct][r] - mx);
        s[ct][r] = e;
        sm += e;
      }
      sm += __shfl_xor(sm, 1);
      sm += __shfl_xor(sm, 2);
      sm += __shfl_xor(sm, 4);
      sm += __shfl_xor(sm, 8);
      rsum[r] = 1.0f / sm;
    }

    // write P (unnormalized, bounded by 1) as bf16; wave-local rows -> no barrier
#pragma unroll
    for (int ct = 0; ct < 4; ++ct)
#pragma unroll
      for (int r = 0; r < 4; ++r)
        p_lds[(w * 16 + lq * 4 + r) * PSTR + ct * 16 + l15] = f2bf(s[ct][r]);

    // PV: out_h rows (16 x 32), K=64 (2 k-steps)
    f32x4 o[2];
    o[0] = zero4; o[1] = zero4;
#pragma unroll
    for (int kk = 0; kk < 2; ++kk) {
      const bf16x8 ap = *(const bf16x8*)&p_lds[(w * 16 + l15) * PSTR + kk * 32 + lq * 8];
#pragma unroll
      for (int ct = 0; ct < 2; ++ct) {
        const bf16x8 bv = *(const bf16x8*)&vT_lds[(h * 32 + ct * 16 + l15) * VSTR + kk * 32 + lq * 8];
        o[ct] = mfma16(ap, bv, o[ct]);
      }
    }
    // normalize rows, stash as bf16 (wave-local)
#pragma unroll
    for (int ct = 0; ct < 2; ++ct)
#pragma unroll
      for (int r = 0; r < 4; ++r)
        oh_lds[(w * 16 + lq * 4 + r) * OSTR + ct * 16 + l15] = f2bf(o[ct][r] * rsum[r]);

    // out-proj slice: ACC(16x256) += oh(16x32) @ w_out[h*32:(h+1)*32, :]
    const bf16x8 ao = *(const bf16x8*)&oh_lds[(w * 16 + l15) * OSTR + lq * 8];
#pragma unroll
    for (int ct = 0; ct < 16; ++ct) {
      const bf16x8 bw = *(const bf16x8*)&woutT[(size_t)(ct * 16 + l15) * 256 + h * 32 + lq * 8];
      ACC[ct] = mfma16(ao, bw, ACC[ct]);
    }
  }

  // ---------- phase 4: epilogue, fp32 write + bias ----------
  {
    const size_t img_base = (size_t)img * 128 * 128 * 256;
#pragma unroll
    for (int ct = 0; ct < 16; ++ct) {
      const int n = ct * 16 + l15;
      const float bo = b_out[n];
#pragma unroll
      for (int r = 0; r < 4; ++r) {
        const int p = w * 16 + lq * 4 + r;
        const size_t off = img_base +
            (((size_t)(wy * 8 + (p >> 3)) * 128) + (wx * 8 + (p & 7))) * 256 + n;
        out[off] = ACC[ct][r] + bo;
      }
    }
  }
}

extern "C" void kernel_launch(void* const* d_in, const int* in_sizes, int n_in,
                              void* d_out, int out_size, void* d_ws, size_t ws_size,
                              hipStream_t stream) {
  const float* x       = (const float*)d_in[0];
  const float* w_qkv   = (const float*)d_in[1];
  const float* pos_emb = (const float*)d_in[2];
  const float* w_out   = (const float*)d_in[3];
  const float* b_out   = (const float*)d_in[4];
  float* out = (float*)d_out;

  // workspace layout: wqkvT (768*256 bf16) | woutT (256*256 bf16) | bias64 (64*64 f32)
  unsigned short* wqkvT = (unsigned short*)d_ws;
  unsigned short* woutT = wqkvT + 768 * 256;
  float* bias64 = (float*)(woutT + 256 * 256);

  prep_kernel<<<96, 256, 0, stream>>>(w_qkv, w_out, pos_emb, wqkvT, woutT, bias64);
  winattn_kernel<<<2048, 256, 0, stream>>>(x, wqkvT, woutT, bias64, b_out, out);
}